// Round 7
// baseline (868.564 us; speedup 1.0000x reference)
//
#include <hip/hip_runtime.h>
#include <hip/hip_bf16.h>

#define BATCH 16
#define CH 256
#define HH 128
#define WW 128
#define HWSZ (HH * WW)
#define NHEAD 8
#define DHEAD 32
#define PW 132       // padded spatial width  (2 halo each side)
#define PPIX (132 * 132)

typedef __attribute__((ext_vector_type(8))) short bf16x8;
typedef __attribute__((ext_vector_type(4))) float f32x4;
typedef _Float16 h2v __attribute__((ext_vector_type(2)));

__device__ __forceinline__ unsigned short f2b(float f) {
    unsigned u = __builtin_bit_cast(unsigned, f);
    u += 0x7fffu + ((u >> 16) & 1u);   // RNE
    return (unsigned short)(u >> 16);
}
__device__ __forceinline__ unsigned short f2h(float f) {
    _Float16 h = (_Float16)f;
    return __builtin_bit_cast(unsigned short, h);
}

#if __has_builtin(__builtin_amdgcn_fdot2)
#define DOT2(a, b, c) __builtin_amdgcn_fdot2((a), (b), (c), false)
#else
#define DOT2(a, b, c) ((c) + (float)(a).x * (float)(b).x + (float)(a).y * (float)(b).y)
#endif

// ---------------------------------------------------------------------------
// Kernel Z: zero the spatial border of padded K/V buffers (1040 px per b,h).
// ---------------------------------------------------------------------------
__global__ __launch_bounds__(256)
void zpad_kernel(unsigned short* __restrict__ kpad, unsigned short* __restrict__ vpad)
{
    int bid = blockIdx.x;  // 0..255 : (bh, tensor)
    unsigned short* dst = ((bid & 1) ? vpad : kpad) + (size_t)(bid >> 1) * PPIX * DHEAD;
    const uint4 z = {0u, 0u, 0u, 0u};
    for (int i = threadIdx.x; i < 1040; i += 256) {
        int row, col;
        if (i < 264)      { row = i / 132; col = i - row * 132; }
        else if (i < 528) { int j = i - 264; int r = j / 132; row = 130 + r; col = j - r * 132; }
        else              { int j = i - 528; row = 2 + (j >> 2); int c = j & 3; col = (c < 2) ? c : (128 + c); }
        uint4* p = reinterpret_cast<uint4*>(dst + (size_t)(row * PW + col) * DHEAD);
        p[0] = z; p[1] = z; p[2] = z; p[3] = z;
    }
}

// ---------------------------------------------------------------------------
// Kernel 0: convert wq|wk|wv|wfc fp32 -> bf16, stashed in d_ws tail.
// ---------------------------------------------------------------------------
__global__ __launch_bounds__(256)
void prep_kernel(const float* __restrict__ wq, const float* __restrict__ wk,
                 const float* __restrict__ wv, const float* __restrict__ wfc,
                 unsigned short* __restrict__ wb)
{
    const float* src = (blockIdx.y == 0) ? wq : (blockIdx.y == 1) ? wk
                     : (blockIdx.y == 2) ? wv : wfc;
    unsigned short* dst = wb + blockIdx.y * 65536;
    int e = (blockIdx.x * 256 + threadIdx.x) * 8;
    const float4* s = reinterpret_cast<const float4*>(src + e);
    float4 a = s[0], c = s[1];
    uint4 u;
    u.x = (unsigned)f2b(a.x) | ((unsigned)f2b(a.y) << 16);
    u.y = (unsigned)f2b(a.z) | ((unsigned)f2b(a.w) << 16);
    u.z = (unsigned)f2b(c.x) | ((unsigned)f2b(c.y) << 16);
    u.w = (unsigned)f2b(c.z) | ((unsigned)f2b(c.w) << 16);
    *reinterpret_cast<uint4*>(dst + e) = u;
}

// ---------------------------------------------------------------------------
// Kernel 1: projections -> f16, pixel-major. BM=256 out ch, BN=128 px, BK=32.
// A-fragments read DIRECTLY from global bf16 W (L2-resident) - no lA stage.
// lB: LDST=32, slot-XOR swizzle, double-buffered -> one barrier per ks.
// ---------------------------------------------------------------------------
__global__ __launch_bounds__(512)
void proj_kernel(const float* __restrict__ q, const float* __restrict__ k,
                 const float* __restrict__ v, const unsigned short* __restrict__ wb,
                 unsigned short* __restrict__ qh, unsigned short* __restrict__ kpad,
                 unsigned short* __restrict__ vpad)
{
    __shared__ __align__(16) unsigned short lB[2][128 * 32];  // 16 KB

    const int t = threadIdx.x;
    const int b = blockIdx.y;
    const int p0 = blockIdx.x * 128;
    const int z = blockIdx.z;

    const float* X; unsigned short* Y;
    if (z == 0)      { X = q; Y = qh; }
    else if (z == 1) { X = k; Y = kpad; }
    else             { X = v; Y = vpad; }
    const unsigned short* Wb = wb + z * 65536;
    X += (size_t)b * CH * HWSZ;
    const size_t pixstride = (z == 0) ? (size_t)HWSZ : (size_t)PPIX;
    Y += (size_t)b * NHEAD * pixstride * DHEAD;

    const int lane = t & 63;
    const int wid  = t >> 6;   // 0..7
    const int wm   = wid & 3;  // out-channel quadrant (64 rows)
    const int wn   = wid >> 2; // pixel half (64 px)
    const int lrow = lane & 15;
    const int lkg  = lane >> 4;
    const int pB   = t & 127;  // staging pixel
    const int cg   = t >> 7;   // staging channel quarter

    f32x4 acc[4][4];
    const f32x4 zero = {0.f, 0.f, 0.f, 0.f};
#pragma unroll
    for (int m = 0; m < 4; ++m)
#pragma unroll
        for (int n = 0; n < 4; ++n) acc[m][n] = zero;

    for (int ks = 0; ks < 8; ++ks) {
        const int k0 = ks * 32;
        // stage B (transposed fp32 -> bf16), XOR slot swizzle
        {
            const float* xp = X + (size_t)(k0 + cg * 8) * HWSZ + p0 + pB;
            float fv[8];
#pragma unroll
            for (int i = 0; i < 8; ++i) fv[i] = xp[(size_t)i * HWSZ];
            uint4 u;
            u.x = (unsigned)f2b(fv[0]) | ((unsigned)f2b(fv[1]) << 16);
            u.y = (unsigned)f2b(fv[2]) | ((unsigned)f2b(fv[3]) << 16);
            u.z = (unsigned)f2b(fv[4]) | ((unsigned)f2b(fv[5]) << 16);
            u.w = (unsigned)f2b(fv[6]) | ((unsigned)f2b(fv[7]) << 16);
            *reinterpret_cast<uint4*>(&lB[ks & 1][pB * 32 + ((cg ^ (pB & 3)) << 3)]) = u;
        }
        __syncthreads();

        bf16x8 af[4], bfv[4];
#pragma unroll
        for (int m = 0; m < 4; ++m)
            af[m] = *reinterpret_cast<const bf16x8*>(Wb + (wm * 64 + m * 16 + lrow) * 256 + k0 + lkg * 8);
#pragma unroll
        for (int n = 0; n < 4; ++n)
            bfv[n] = *reinterpret_cast<const bf16x8*>(&lB[ks & 1][(wn * 64 + n * 16 + lrow) * 32 + ((lkg ^ (lrow & 3)) << 3)]);
#pragma unroll
        for (int m = 0; m < 4; ++m)
#pragma unroll
            for (int n = 0; n < 4; ++n)
                acc[m][n] = __builtin_amdgcn_mfma_f32_16x16x32_bf16(af[m], bfv[n], acc[m][n], 0, 0, 0);
        // no second barrier: next iter writes the other buffer
    }

    const int lr = lane >> 4, lc = lane & 15;
#pragma unroll
    for (int m = 0; m < 4; ++m)
#pragma unroll
        for (int n = 0; n < 4; ++n) {
            int o = wm * 64 + m * 16 + lr * 4;
            int hh_ = o >> 5, d0 = o & 31;
            int p = p0 + wn * 64 + n * 16 + lc;
            ushort4 pk;
            pk.x = f2h(acc[m][n][0]); pk.y = f2h(acc[m][n][1]);
            pk.z = f2h(acc[m][n][2]); pk.w = f2h(acc[m][n][3]);
            size_t pix;
            if (z == 0) pix = (size_t)hh_ * HWSZ + p;
            else { int row = p >> 7, col = p & 127; pix = (size_t)hh_ * PPIX + (size_t)(row + 2) * PW + (col + 2); }
            *reinterpret_cast<ushort4*>(&Y[pix * DHEAD + d0]) = pk;
        }
}

// ---------------------------------------------------------------------------
// Kernel 2: local 5x5 attention — 4 lanes per pixel, contiguous 1KB/wave
// accesses, dot2 + shfl butterfly. Unchanged from R6.
// ---------------------------------------------------------------------------
__global__ __launch_bounds__(1024)
void attn_kernel(unsigned short* __restrict__ qh,
                 const unsigned short* __restrict__ kpad,
                 const unsigned short* __restrict__ vpad)
{
    const int t = threadIdx.x;
    const int swz = (blockIdx.x & 7) * 1024 + (blockIdx.x >> 3);
    const int bh = swz >> 6;
    const int tile = swz & 63;
    const int x0 = (tile & 7) * 16, y0 = (tile >> 3) * 16;
    const int qc = t & 3;
    const int px = (t >> 2) & 15;
    const int py = t >> 6;
    const int gx = x0 + px, gy = y0 + py;

    unsigned short* qp = qh + ((size_t)bh * HWSZ + gy * WW + gx) * DHEAD + qc * 8;
    const unsigned short* kb = kpad + (size_t)bh * PPIX * DHEAD + qc * 8;
    const unsigned short* vb = vpad + (size_t)bh * PPIX * DHEAD + qc * 8;

    union { uint4 u; h2v h2[4]; } Q;
    Q.u = *reinterpret_cast<const uint4*>(qp);

    float ew[25];
#pragma unroll
    for (int wy = 0; wy < 5; ++wy) {
        const unsigned short* krow = kb + (size_t)((gy + wy) * PW + gx) * DHEAD;
#pragma unroll
        for (int wx = 0; wx < 5; ++wx) {
            union { uint4 u; h2v h2[4]; } K;
            K.u = *reinterpret_cast<const uint4*>(krow + wx * DHEAD);
            float s = 0.f;
#pragma unroll
            for (int j = 0; j < 4; ++j)
                s = DOT2(Q.h2[j], K.h2[j], s);
            s += __shfl_xor(s, 1);
            s += __shfl_xor(s, 2);
            ew[wy * 5 + wx] = __expf(fmaxf(s, 0.f) * 0.17677669529663687f);
        }
    }

    float sum = 0.f;
#pragma unroll
    for (int i = 0; i < 25; ++i) sum += ew[i];
    const float inv = 1.f / sum;

    union { uint4 u; h2v h2[4]; } A;
    const h2v hz = {(_Float16)0.f, (_Float16)0.f};
#pragma unroll
    for (int j = 0; j < 4; ++j) A.h2[j] = hz;

#pragma unroll
    for (int wy = 0; wy < 5; ++wy) {
        const unsigned short* vrow = vb + (size_t)((gy + wy) * PW + gx) * DHEAD;
#pragma unroll
        for (int wx = 0; wx < 5; ++wx) {
            _Float16 wh = (_Float16)(ew[wy * 5 + wx] * inv);
            h2v w2 = {wh, wh};
            union { uint4 u; h2v h2[4]; } V;
            V.u = *reinterpret_cast<const uint4*>(vrow + wx * DHEAD);
#pragma unroll
            for (int j = 0; j < 4; ++j)
                A.h2[j] += w2 * V.h2[j];
        }
    }

    *reinterpret_cast<uint4*>(qp) = A.u;
}

// ---------------------------------------------------------------------------
// Kernel 3: o = wfc @ attn_out + residual, LayerNorm. BN=128 px, 512 thr.
// A-fragments direct from global bf16 wfc; lB dbuf + slot-XOR.
// ---------------------------------------------------------------------------
__global__ __launch_bounds__(512)
void fcln_kernel(const unsigned short* __restrict__ ob, const unsigned short* __restrict__ wfcb,
                 const float* __restrict__ qres, const float* __restrict__ lnw,
                 const float* __restrict__ lnb, float* __restrict__ out)
{
    __shared__ __align__(16) unsigned short lB[2][128 * 32];  // 16 KB
    __shared__ float lsum[8][128];
    __shared__ float lssq[8][128];

    const int t = threadIdx.x;
    const int b = blockIdx.y;
    const int p0 = blockIdx.x * 128;

    const int lane = t & 63;
    const int wid  = t >> 6;
    const int wm   = wid & 3;
    const int wn   = wid >> 2;
    const int lrow = lane & 15;
    const int lkg  = lane >> 4;
    const int pxs  = t >> 2;    // staging pixel (0..127)
    const int qcs  = t & 3;     // staging quarter

    f32x4 acc[4][4];
    const f32x4 zero = {0.f, 0.f, 0.f, 0.f};
#pragma unroll
    for (int m = 0; m < 4; ++m)
#pragma unroll
        for (int n = 0; n < 4; ++n) acc[m][n] = zero;

    for (int ks = 0; ks < 8; ++ks) {
        const int k0 = ks * 32;
        {
            const unsigned short* obb = ob + (size_t)(b * NHEAD + ks) * HWSZ * DHEAD;
            uint4 bv = *reinterpret_cast<const uint4*>(obb + (size_t)(p0 + pxs) * DHEAD + qcs * 8);
            uint4 o4;  // f16 -> bf16
            {
                h2v h;
                h = __builtin_bit_cast(h2v, bv.x); o4.x = (unsigned)f2b((float)h.x) | ((unsigned)f2b((float)h.y) << 16);
                h = __builtin_bit_cast(h2v, bv.y); o4.y = (unsigned)f2b((float)h.x) | ((unsigned)f2b((float)h.y) << 16);
                h = __builtin_bit_cast(h2v, bv.z); o4.z = (unsigned)f2b((float)h.x) | ((unsigned)f2b((float)h.y) << 16);
                h = __builtin_bit_cast(h2v, bv.w); o4.w = (unsigned)f2b((float)h.x) | ((unsigned)f2b((float)h.y) << 16);
            }
            *reinterpret_cast<uint4*>(&lB[ks & 1][pxs * 32 + ((qcs ^ (pxs & 3)) << 3)]) = o4;
        }
        __syncthreads();

        bf16x8 af[4], bfv[4];
#pragma unroll
        for (int m = 0; m < 4; ++m)
            af[m] = *reinterpret_cast<const bf16x8*>(wfcb + (wm * 64 + m * 16 + lrow) * 256 + k0 + lkg * 8);
#pragma unroll
        for (int n = 0; n < 4; ++n)
            bfv[n] = *reinterpret_cast<const bf16x8*>(&lB[ks & 1][(wn * 64 + n * 16 + lrow) * 32 + ((lkg ^ (lrow & 3)) << 3)]);
#pragma unroll
        for (int m = 0; m < 4; ++m)
#pragma unroll
            for (int n = 0; n < 4; ++n)
                acc[m][n] = __builtin_amdgcn_mfma_f32_16x16x32_bf16(af[m], bfv[n], acc[m][n], 0, 0, 0);
    }

    const int lr = lane >> 4, lc = lane & 15;
    const float* qb = qres + (size_t)b * CH * HWSZ;
#pragma unroll
    for (int m = 0; m < 4; ++m)
#pragma unroll
        for (int n = 0; n < 4; ++n)
#pragma unroll
            for (int j = 0; j < 4; ++j) {
                int o = wm * 64 + m * 16 + lr * 4 + j;
                int p = p0 + wn * 64 + n * 16 + lc;
                acc[m][n][j] += qb[(size_t)o * HWSZ + p];
            }

    float s[4], s2[4];
#pragma unroll
    for (int n = 0; n < 4; ++n) {
        float a = 0.f, c2 = 0.f;
#pragma unroll
        for (int m = 0; m < 4; ++m)
#pragma unroll
            for (int j = 0; j < 4; ++j) {
                float x = acc[m][n][j];
                a += x; c2 += x * x;
            }
        a  += __shfl_xor(a, 16);  a  += __shfl_xor(a, 32);
        c2 += __shfl_xor(c2, 16); c2 += __shfl_xor(c2, 32);
        s[n] = a; s2[n] = c2;
    }
    __syncthreads();   // lB no longer needed; reuse-safe ordering for lsum
    if (lane < 16) {
#pragma unroll
        for (int n = 0; n < 4; ++n) {
            lsum[wid][wn * 64 + n * 16 + lane] = s[n];
            lssq[wid][wn * 64 + n * 16 + lane] = s2[n];
        }
    }
    __syncthreads();

    float mu[4], rs[4];
#pragma unroll
    for (int n = 0; n < 4; ++n) {
        int p = wn * 64 + n * 16 + lc;
        float ts = lsum[wn * 4 + 0][p] + lsum[wn * 4 + 1][p] + lsum[wn * 4 + 2][p] + lsum[wn * 4 + 3][p];
        float tq = lssq[wn * 4 + 0][p] + lssq[wn * 4 + 1][p] + lssq[wn * 4 + 2][p] + lssq[wn * 4 + 3][p];
        float m_ = ts * (1.f / 256.f);
        float v_ = tq * (1.f / 256.f) - m_ * m_;
        mu[n] = m_;
        rs[n] = rsqrtf(v_ + 1e-6f);
    }

    float* op = out + (size_t)b * CH * HWSZ;
#pragma unroll
    for (int m = 0; m < 4; ++m)
#pragma unroll
        for (int j = 0; j < 4; ++j) {
            int o = wm * 64 + m * 16 + lr * 4 + j;
            float g = lnw[o], bb = lnb[o];
#pragma unroll
            for (int n = 0; n < 4; ++n) {
                int p = p0 + wn * 64 + n * 16 + lc;
                op[(size_t)o * HWSZ + p] = (acc[m][n][j] - mu[n]) * rs[n] * g + bb;
            }
        }
}

extern "C" void kernel_launch(void* const* d_in, const int* in_sizes, int n_in,
                              void* d_out, int out_size, void* d_ws, size_t ws_size,
                              hipStream_t stream) {
    const float* q   = (const float*)d_in[0];
    const float* k   = (const float*)d_in[1];
    const float* v   = (const float*)d_in[2];
    const float* wq  = (const float*)d_in[3];
    const float* wk  = (const float*)d_in[4];
    const float* wv  = (const float*)d_in[5];
    const float* wfc = (const float*)d_in[6];
    const float* lnw = (const float*)d_in[7];
    const float* lnb = (const float*)d_in[8];

    const size_t qsz = (size_t)BATCH * NHEAD * HWSZ * DHEAD;   // 67,108,864
    const size_t psz = (size_t)BATCH * NHEAD * PPIX * DHEAD;   // 71,368,704
    if (ws_size < (qsz + 2 * psz + 4 * 65536) * sizeof(unsigned short)) return;

    unsigned short* qh = (unsigned short*)d_ws;   // q proj, then attn output (in place)
    unsigned short* kp = qh + qsz;
    unsigned short* vp = kp + psz;
    unsigned short* wb = vp + psz;                // 512KB bf16 weight stash (wq|wk|wv|wfc)

    zpad_kernel<<<256, 256, 0, stream>>>(kp, vp);
    prep_kernel<<<dim3(32, 4), 256, 0, stream>>>(wq, wk, wv, wfc, wb);
    proj_kernel<<<dim3(HWSZ / 128, BATCH, 3), 512, 0, stream>>>(q, k, v, wb, qh, kp, vp);
    attn_kernel<<<8192, 1024, 0, stream>>>(qh, kp, vp);
    fcln_kernel<<<dim3(HWSZ / 128, BATCH), 512, 0, stream>>>(qh, wb + 3 * 65536, q, lnw, lnb, (float*)d_out);
}

// Round 9
// 798.460 us; speedup vs baseline: 1.0878x; 1.0878x over previous
//
#include <hip/hip_runtime.h>
#include <hip/hip_bf16.h>

#define BATCH 16
#define CH 256
#define HH 128
#define WW 128
#define HWSZ (HH * WW)
#define NHEAD 8
#define DHEAD 32
#define PW 132       // padded spatial width  (2 halo each side)
#define PPIX (132 * 132)
#define LDSTB 40     // lB row stride in shorts: word stride 20, <=2-way banks

typedef __attribute__((ext_vector_type(8))) short bf16x8;
typedef __attribute__((ext_vector_type(4))) float f32x4;
typedef _Float16 h2v __attribute__((ext_vector_type(2)));

__device__ __forceinline__ unsigned short f2b(float f) {
    unsigned u = __builtin_bit_cast(unsigned, f);
    u += 0x7fffu + ((u >> 16) & 1u);   // RNE
    return (unsigned short)(u >> 16);
}
__device__ __forceinline__ unsigned short f2h(float f) {
    _Float16 h = (_Float16)f;
    return __builtin_bit_cast(unsigned short, h);
}
// packed f32x2 -> bf16x2 in one u32 (v_cvt_pk_bf16_f32 on gfx950)
__device__ __forceinline__ unsigned pkbf(float a, float b) {
    __hip_bfloat162_raw r = __hip_bfloat162_raw(__float22bfloat162_rn(make_float2(a, b)));
    return (unsigned)r.x | ((unsigned)r.y << 16);
}

#if __has_builtin(__builtin_amdgcn_fdot2)
#define DOT2(a, b, c) __builtin_amdgcn_fdot2((a), (b), (c), false)
#else
#define DOT2(a, b, c) ((c) + (float)(a)[0] * (float)(b)[0] + (float)(a)[1] * (float)(b)[1])
#endif

// ---------------------------------------------------------------------------
// Kernel Z: zero the spatial border of padded K/V buffers (1040 px per b,h).
// ---------------------------------------------------------------------------
__global__ __launch_bounds__(256)
void zpad_kernel(unsigned short* __restrict__ kpad, unsigned short* __restrict__ vpad)
{
    int bid = blockIdx.x;  // 0..255 : (bh, tensor)
    unsigned short* dst = ((bid & 1) ? vpad : kpad) + (size_t)(bid >> 1) * PPIX * DHEAD;
    const uint4 z = {0u, 0u, 0u, 0u};
    for (int i = threadIdx.x; i < 1040; i += 256) {
        int row, col;
        if (i < 264)      { row = i / 132; col = i - row * 132; }
        else if (i < 528) { int j = i - 264; int r = j / 132; row = 130 + r; col = j - r * 132; }
        else              { int j = i - 528; row = 2 + (j >> 2); int c = j & 3; col = (c < 2) ? c : (128 + c); }
        uint4* p = reinterpret_cast<uint4*>(dst + (size_t)(row * PW + col) * DHEAD);
        p[0] = z; p[1] = z; p[2] = z; p[3] = z;
    }
}

// ---------------------------------------------------------------------------
// Kernel 0: convert wq|wk|wv|wfc fp32 -> bf16, stashed in d_ws tail.
// ---------------------------------------------------------------------------
__global__ __launch_bounds__(256)
void prep_kernel(const float* __restrict__ wq, const float* __restrict__ wk,
                 const float* __restrict__ wv, const float* __restrict__ wfc,
                 unsigned short* __restrict__ wb)
{
    const float* src = (blockIdx.y == 0) ? wq : (blockIdx.y == 1) ? wk
                     : (blockIdx.y == 2) ? wv : wfc;
    unsigned short* dst = wb + blockIdx.y * 65536;
    int e = (blockIdx.x * 256 + threadIdx.x) * 8;
    const float4* s = reinterpret_cast<const float4*>(src + e);
    float4 a = s[0], c = s[1];
    uint4 u;
    u.x = pkbf(a.x, a.y); u.y = pkbf(a.z, a.w);
    u.z = pkbf(c.x, c.y); u.w = pkbf(c.z, c.w);
    *reinterpret_cast<uint4*>(dst + e) = u;
}

// ---------------------------------------------------------------------------
// Kernel 1: projections -> f16, pixel-major. BM=256, BN=64, BK=32, 4 waves.
// A-fragments direct from global bf16 W with 1-iter register prefetch;
// lB double-buffered + reg-prefetched; ONE barrier per ks.
// ---------------------------------------------------------------------------
__global__ __launch_bounds__(256)
void proj_kernel(const float* __restrict__ q, const float* __restrict__ k,
                 const float* __restrict__ v, const unsigned short* __restrict__ wb,
                 unsigned short* __restrict__ qh, unsigned short* __restrict__ kpad,
                 unsigned short* __restrict__ vpad)
{
    __shared__ __align__(16) unsigned short lB[2][64 * LDSTB];  // 10 KB

    const int t = threadIdx.x;
    const int b = blockIdx.y;
    const int p0 = blockIdx.x * 64;
    const int z = blockIdx.z;

    const float* X; unsigned short* Y;
    if (z == 0)      { X = q; Y = qh; }
    else if (z == 1) { X = k; Y = kpad; }
    else             { X = v; Y = vpad; }
    const unsigned short* Wb = wb + z * 65536;
    X += (size_t)b * CH * HWSZ;
    const size_t pixstride = (z == 0) ? (size_t)HWSZ : (size_t)PPIX;
    Y += (size_t)b * NHEAD * pixstride * DHEAD;

    const int lane = t & 63;
    const int wid  = t >> 6;   // m-quadrant 0..3
    const int lrow = lane & 15;
    const int lkg  = lane >> 4;
    const int pB   = t & 63;   // staging pixel
    const int cg   = t >> 6;   // staging channel quarter (8 ch)

    // prologue: prefetch B regs and A frags for ks=0
    float fv[8];
    {
        const float* xp = X + (size_t)(cg * 8) * HWSZ + p0 + pB;
#pragma unroll
        for (int i = 0; i < 8; ++i) fv[i] = xp[(size_t)i * HWSZ];
    }
    bf16x8 afc[4], afn[4];
#pragma unroll
    for (int m = 0; m < 4; ++m)
        afc[m] = *reinterpret_cast<const bf16x8*>(Wb + (wid * 64 + m * 16 + lrow) * 256 + lkg * 8);

    f32x4 acc[4][4];
    const f32x4 zero = {0.f, 0.f, 0.f, 0.f};
#pragma unroll
    for (int m = 0; m < 4; ++m)
#pragma unroll
        for (int n = 0; n < 4; ++n) acc[m][n] = zero;

    for (int ks = 0; ks < 8; ++ks) {
        // pack current B tile -> LDS
        {
            uint4 u;
            u.x = pkbf(fv[0], fv[1]); u.y = pkbf(fv[2], fv[3]);
            u.z = pkbf(fv[4], fv[5]); u.w = pkbf(fv[6], fv[7]);
            *reinterpret_cast<uint4*>(&lB[ks & 1][pB * LDSTB + cg * 8]) = u;
        }
        // prefetch next B into regs (issue-early)
        if (ks < 7) {
            const float* xp = X + (size_t)((ks + 1) * 32 + cg * 8) * HWSZ + p0 + pB;
#pragma unroll
            for (int i = 0; i < 8; ++i) fv[i] = xp[(size_t)i * HWSZ];
        }
        __syncthreads();
        // prefetch next A frags (L2-resident W)
        if (ks < 7) {
#pragma unroll
            for (int m = 0; m < 4; ++m)
                afn[m] = *reinterpret_cast<const bf16x8*>(Wb + (wid * 64 + m * 16 + lrow) * 256 + (ks + 1) * 32 + lkg * 8);
        }
        bf16x8 bfv[4];
#pragma unroll
        for (int n = 0; n < 4; ++n)
            bfv[n] = *reinterpret_cast<const bf16x8*>(&lB[ks & 1][(n * 16 + lrow) * LDSTB + lkg * 8]);
#pragma unroll
        for (int m = 0; m < 4; ++m)
#pragma unroll
            for (int n = 0; n < 4; ++n)
                acc[m][n] = __builtin_amdgcn_mfma_f32_16x16x32_bf16(afc[m], bfv[n], acc[m][n], 0, 0, 0);
#pragma unroll
        for (int m = 0; m < 4; ++m) afc[m] = afn[m];
    }

    const int lr = lane >> 4, lc = lane & 15;
#pragma unroll
    for (int m = 0; m < 4; ++m)
#pragma unroll
        for (int n = 0; n < 4; ++n) {
            int o = wid * 64 + m * 16 + lr * 4;
            int hh_ = o >> 5, d0 = o & 31;
            int p = p0 + n * 16 + lc;
            ushort4 pk;
            pk.x = f2h(acc[m][n][0]); pk.y = f2h(acc[m][n][1]);
            pk.z = f2h(acc[m][n][2]); pk.w = f2h(acc[m][n][3]);
            size_t pix;
            if (z == 0) pix = (size_t)hh_ * HWSZ + p;
            else { int row = p >> 7, col = p & 127; pix = (size_t)hh_ * PPIX + (size_t)(row + 2) * PW + (col + 2); }
            *reinterpret_cast<ushort4*>(&Y[pix * DHEAD + d0]) = pk;
        }
}

// ---------------------------------------------------------------------------
// Kernel 2: local 5x5 attention — 4 lanes per pixel, contiguous 1KB/wave.
// Output converted to BF16 (pixel-major, in place over qh).
// ---------------------------------------------------------------------------
__global__ __launch_bounds__(1024)
void attn_kernel(unsigned short* __restrict__ qh,
                 const unsigned short* __restrict__ kpad,
                 const unsigned short* __restrict__ vpad)
{
    const int t = threadIdx.x;
    const int swz = (blockIdx.x & 7) * 1024 + (blockIdx.x >> 3);
    const int bh = swz >> 6;
    const int tile = swz & 63;
    const int x0 = (tile & 7) * 16, y0 = (tile >> 3) * 16;
    const int qc = t & 3;
    const int px = (t >> 2) & 15;
    const int py = t >> 6;
    const int gx = x0 + px, gy = y0 + py;

    unsigned short* qp = qh + ((size_t)bh * HWSZ + gy * WW + gx) * DHEAD + qc * 8;
    const unsigned short* kb = kpad + (size_t)bh * PPIX * DHEAD + qc * 8;
    const unsigned short* vb = vpad + (size_t)bh * PPIX * DHEAD + qc * 8;

    union { uint4 u; h2v h2[4]; } Q;
    Q.u = *reinterpret_cast<const uint4*>(qp);

    float ew[25];
#pragma unroll
    for (int wy = 0; wy < 5; ++wy) {
        const unsigned short* krow = kb + (size_t)((gy + wy) * PW + gx) * DHEAD;
#pragma unroll
        for (int wx = 0; wx < 5; ++wx) {
            union { uint4 u; h2v h2[4]; } K;
            K.u = *reinterpret_cast<const uint4*>(krow + wx * DHEAD);
            float s = 0.f;
#pragma unroll
            for (int j = 0; j < 4; ++j)
                s = DOT2(Q.h2[j], K.h2[j], s);
            s += __shfl_xor(s, 1);
            s += __shfl_xor(s, 2);
            ew[wy * 5 + wx] = __expf(fmaxf(s, 0.f) * 0.17677669529663687f);
        }
    }

    float sum = 0.f;
#pragma unroll
    for (int i = 0; i < 25; ++i) sum += ew[i];
    const float inv = 1.f / sum;

    union { uint4 u; h2v h2[4]; } A;
    const h2v hz = {(_Float16)0.f, (_Float16)0.f};
#pragma unroll
    for (int j = 0; j < 4; ++j) A.h2[j] = hz;

#pragma unroll
    for (int wy = 0; wy < 5; ++wy) {
        const unsigned short* vrow = vb + (size_t)((gy + wy) * PW + gx) * DHEAD;
#pragma unroll
        for (int wx = 0; wx < 5; ++wx) {
            _Float16 wh = (_Float16)(ew[wy * 5 + wx] * inv);
            h2v w2 = {wh, wh};
            union { uint4 u; h2v h2[4]; } V;
            V.u = *reinterpret_cast<const uint4*>(vrow + wx * DHEAD);
#pragma unroll
            for (int j = 0; j < 4; ++j)
                A.h2[j] += w2 * V.h2[j];
        }
    }

    // f16 acc -> bf16 out (fcln consumes bf16 directly, no cvt in its loop)
    uint4 o;
    o.x = pkbf((float)A.h2[0][0], (float)A.h2[0][1]);
    o.y = pkbf((float)A.h2[1][0], (float)A.h2[1][1]);
    o.z = pkbf((float)A.h2[2][0], (float)A.h2[2][1]);
    o.w = pkbf((float)A.h2[3][0], (float)A.h2[3][1]);
    *reinterpret_cast<uint4*>(qp) = o;
}

// ---------------------------------------------------------------------------
// Kernel 3: o = wfc @ attn_out + residual, LayerNorm. BM=256, BN=64, 4 waves.
// B-stage is a pure 16B copy (bf16 pixel-major); A direct + prefetched.
// ---------------------------------------------------------------------------
__global__ __launch_bounds__(256)
void fcln_kernel(const unsigned short* __restrict__ ob, const unsigned short* __restrict__ wfcb,
                 const float* __restrict__ qres, const float* __restrict__ lnw,
                 const float* __restrict__ lnb, float* __restrict__ out)
{
    __shared__ __align__(16) unsigned short lB[2][64 * LDSTB];  // 10 KB
    __shared__ float lsum[4][64];
    __shared__ float lssq[4][64];

    const int t = threadIdx.x;
    const int b = blockIdx.y;
    const int p0 = blockIdx.x * 64;

    const int lane = t & 63;
    const int wid  = t >> 6;
    const int lrow = lane & 15;
    const int lkg  = lane >> 4;
    const int pxs  = t >> 2;    // staging pixel (0..63)
    const int qcs  = t & 3;     // staging quarter

    // prologue prefetch
    uint4 bv;
    {
        const unsigned short* obb = ob + (size_t)(b * NHEAD + 0) * HWSZ * DHEAD;
        bv = *reinterpret_cast<const uint4*>(obb + (size_t)(p0 + pxs) * DHEAD + qcs * 8);
    }
    bf16x8 afc[4], afn[4];
#pragma unroll
    for (int m = 0; m < 4; ++m)
        afc[m] = *reinterpret_cast<const bf16x8*>(wfcb + (wid * 64 + m * 16 + lrow) * 256 + lkg * 8);

    f32x4 acc[4][4];
    const f32x4 zero = {0.f, 0.f, 0.f, 0.f};
#pragma unroll
    for (int m = 0; m < 4; ++m)
#pragma unroll
        for (int n = 0; n < 4; ++n) acc[m][n] = zero;

    for (int ks = 0; ks < 8; ++ks) {
        *reinterpret_cast<uint4*>(&lB[ks & 1][pxs * LDSTB + qcs * 8]) = bv;
        if (ks < 7) {
            const unsigned short* obb = ob + (size_t)(b * NHEAD + ks + 1) * HWSZ * DHEAD;
            bv = *reinterpret_cast<const uint4*>(obb + (size_t)(p0 + pxs) * DHEAD + qcs * 8);
        }
        __syncthreads();
        if (ks < 7) {
#pragma unroll
            for (int m = 0; m < 4; ++m)
                afn[m] = *reinterpret_cast<const bf16x8*>(wfcb + (wid * 64 + m * 16 + lrow) * 256 + (ks + 1) * 32 + lkg * 8);
        }
        bf16x8 bfv[4];
#pragma unroll
        for (int n = 0; n < 4; ++n)
            bfv[n] = *reinterpret_cast<const bf16x8*>(&lB[ks & 1][(n * 16 + lrow) * LDSTB + lkg * 8]);
#pragma unroll
        for (int m = 0; m < 4; ++m)
#pragma unroll
            for (int n = 0; n < 4; ++n)
                acc[m][n] = __builtin_amdgcn_mfma_f32_16x16x32_bf16(afc[m], bfv[n], acc[m][n], 0, 0, 0);
#pragma unroll
        for (int m = 0; m < 4; ++m) afc[m] = afn[m];
    }

    const int lr = lane >> 4, lc = lane & 15;
    const float* qb = qres + (size_t)b * CH * HWSZ;
#pragma unroll
    for (int m = 0; m < 4; ++m)
#pragma unroll
        for (int n = 0; n < 4; ++n)
#pragma unroll
            for (int j = 0; j < 4; ++j) {
                int o = wid * 64 + m * 16 + lr * 4 + j;
                int p = p0 + n * 16 + lc;
                acc[m][n][j] += qb[(size_t)o * HWSZ + p];
            }

    float s[4], s2[4];
#pragma unroll
    for (int n = 0; n < 4; ++n) {
        float a = 0.f, c2 = 0.f;
#pragma unroll
        for (int m = 0; m < 4; ++m)
#pragma unroll
            for (int j = 0; j < 4; ++j) {
                float x = acc[m][n][j];
                a += x; c2 += x * x;
            }
        a  += __shfl_xor(a, 16);  a  += __shfl_xor(a, 32);
        c2 += __shfl_xor(c2, 16); c2 += __shfl_xor(c2, 32);
        s[n] = a; s2[n] = c2;
    }
    if (lane < 16) {
#pragma unroll
        for (int n = 0; n < 4; ++n) {
            lsum[wid][n * 16 + lane] = s[n];
            lssq[wid][n * 16 + lane] = s2[n];
        }
    }
    __syncthreads();

    float mu[4], rs[4];
#pragma unroll
    for (int n = 0; n < 4; ++n) {
        int p = n * 16 + lc;
        float ts = lsum[0][p] + lsum[1][p] + lsum[2][p] + lsum[3][p];
        float tq = lssq[0][p] + lssq[1][p] + lssq[2][p] + lssq[3][p];
        float m_ = ts * (1.f / 256.f);
        float v_ = tq * (1.f / 256.f) - m_ * m_;
        mu[n] = m_;
        rs[n] = rsqrtf(v_ + 1e-6f);
    }

    float* op = out + (size_t)b * CH * HWSZ;
#pragma unroll
    for (int m = 0; m < 4; ++m)
#pragma unroll
        for (int j = 0; j < 4; ++j) {
            int o = wid * 64 + m * 16 + lr * 4 + j;
            float g = lnw[o], bb = lnb[o];
#pragma unroll
            for (int n = 0; n < 4; ++n) {
                int p = p0 + n * 16 + lc;
                op[(size_t)o * HWSZ + p] = (acc[m][n][j] - mu[n]) * rs[n] * g + bb;
            }
        }
}

extern "C" void kernel_launch(void* const* d_in, const int* in_sizes, int n_in,
                              void* d_out, int out_size, void* d_ws, size_t ws_size,
                              hipStream_t stream) {
    const float* q   = (const float*)d_in[0];
    const float* k   = (const float*)d_in[1];
    const float* v   = (const float*)d_in[2];
    const float* wq  = (const float*)d_in[3];
    const float* wk  = (const float*)d_in[4];
    const float* wv  = (const float*)d_in[5];
    const float* wfc = (const float*)d_in[6];
    const float* lnw = (const float*)d_in[7];
    const float* lnb = (const float*)d_in[8];

    const size_t qsz = (size_t)BATCH * NHEAD * HWSZ * DHEAD;   // 67,108,864
    const size_t psz = (size_t)BATCH * NHEAD * PPIX * DHEAD;   // 71,368,704
    if (ws_size < (qsz + 2 * psz + 4 * 65536) * sizeof(unsigned short)) return;

    unsigned short* qh = (unsigned short*)d_ws;   // q proj (f16), then attn output (bf16, in place)
    unsigned short* kp = qh + qsz;
    unsigned short* vp = kp + psz;
    unsigned short* wb = vp + psz;                // 512KB bf16 weight stash (wq|wk|wv|wfc)

    zpad_kernel<<<256, 256, 0, stream>>>(kp, vp);
    prep_kernel<<<dim3(32, 4), 256, 0, stream>>>(wq, wk, wv, wfc, wb);
    proj_kernel<<<dim3(HWSZ / 64, BATCH, 3), 256, 0, stream>>>(q, k, v, wb, qh, kp, vp);
    attn_kernel<<<8192, 1024, 0, stream>>>(qh, kp, vp);
    fcln_kernel<<<dim3(HWSZ / 64, BATCH), 256, 0, stream>>>(qh, wb + 3 * 65536, q, lnw, lnb, (float*)d_out);
}

// Round 10
// 776.492 us; speedup vs baseline: 1.1186x; 1.0283x over previous
//
#include <hip/hip_runtime.h>
#include <hip/hip_bf16.h>

#define BATCH 16
#define CH 256
#define HH 128
#define WW 128
#define HWSZ (HH * WW)
#define NHEAD 8
#define DHEAD 32
#define PW 132       // padded spatial width  (2 halo each side)
#define PPIX (132 * 132)
#define ROWS 264     // LDS row stride in shorts (264x2=528B, 16B-aligned; rows 8 apart = 2-way, free)

typedef __attribute__((ext_vector_type(8))) short bf16x8;
typedef __attribute__((ext_vector_type(4))) float f32x4;
typedef _Float16 h2v __attribute__((ext_vector_type(2)));

__device__ __forceinline__ unsigned short f2h(float f) {
    _Float16 h = (_Float16)f;
    return __builtin_bit_cast(unsigned short, h);
}
// packed f32x2 -> bf16x2 in one u32 (v_cvt_pk_bf16_f32 on gfx950)
__device__ __forceinline__ unsigned pkbf(float a, float b) {
    __hip_bfloat162_raw r = __hip_bfloat162_raw(__float22bfloat162_rn(make_float2(a, b)));
    return (unsigned)r.x | ((unsigned)r.y << 16);
}

#if __has_builtin(__builtin_amdgcn_fdot2)
#define DOT2(a, b, c) __builtin_amdgcn_fdot2((a), (b), (c), false)
#else
#define DOT2(a, b, c) ((c) + (float)(a)[0] * (float)(b)[0] + (float)(a)[1] * (float)(b)[1])
#endif

// ---------------------------------------------------------------------------
// Kernel Z: zero the spatial border of padded K/V buffers (1040 px per b,h).
// ---------------------------------------------------------------------------
__global__ __launch_bounds__(256)
void zpad_kernel(unsigned short* __restrict__ kpad, unsigned short* __restrict__ vpad)
{
    int bid = blockIdx.x;  // 0..255 : (bh, tensor)
    unsigned short* dst = ((bid & 1) ? vpad : kpad) + (size_t)(bid >> 1) * PPIX * DHEAD;
    const uint4 z = {0u, 0u, 0u, 0u};
    for (int i = threadIdx.x; i < 1040; i += 256) {
        int row, col;
        if (i < 264)      { row = i / 132; col = i - row * 132; }
        else if (i < 528) { int j = i - 264; int r = j / 132; row = 130 + r; col = j - r * 132; }
        else              { int j = i - 528; row = 2 + (j >> 2); int c = j & 3; col = (c < 2) ? c : (128 + c); }
        uint4* p = reinterpret_cast<uint4*>(dst + (size_t)(row * PW + col) * DHEAD);
        p[0] = z; p[1] = z; p[2] = z; p[3] = z;
    }
}

// ---------------------------------------------------------------------------
// Kernel 0: convert wq|wk|wv|wfc fp32 -> bf16, stashed in d_ws tail.
// ---------------------------------------------------------------------------
__global__ __launch_bounds__(256)
void prep_kernel(const float* __restrict__ wq, const float* __restrict__ wk,
                 const float* __restrict__ wv, const float* __restrict__ wfc,
                 unsigned short* __restrict__ wb)
{
    const float* src = (blockIdx.y == 0) ? wq : (blockIdx.y == 1) ? wk
                     : (blockIdx.y == 2) ? wv : wfc;
    unsigned short* dst = wb + blockIdx.y * 65536;
    int e = (blockIdx.x * 256 + threadIdx.x) * 8;
    const float4* s = reinterpret_cast<const float4*>(src + e);
    float4 a = s[0], c = s[1];
    uint4 u;
    u.x = pkbf(a.x, a.y); u.y = pkbf(a.z, a.w);
    u.z = pkbf(c.x, c.y); u.w = pkbf(c.z, c.w);
    *reinterpret_cast<uint4*>(dst + e) = u;
}

// ---------------------------------------------------------------------------
// Kernel 1: projections -> f16, pixel-major. BM=256, BN=64.
// SINGLE-BARRIER structure: stage the whole 64px x 256ch B-panel (bf16) in
// LDS once, one __syncthreads, then 8 barrier-free ks iterations
// {A-glb prefetch, ds_read, 16 MFMA} the compiler can pipeline freely.
// ---------------------------------------------------------------------------
__global__ __launch_bounds__(256)
void proj_kernel(const float* __restrict__ q, const float* __restrict__ k,
                 const float* __restrict__ v, const unsigned short* __restrict__ wb,
                 unsigned short* __restrict__ qh, unsigned short* __restrict__ kpad,
                 unsigned short* __restrict__ vpad)
{
    __shared__ __align__(16) unsigned short lB[64 * ROWS];  // 33 KB

    const int t = threadIdx.x;
    const int b = blockIdx.y;
    const int p0 = blockIdx.x * 64;
    const int z = blockIdx.z;

    const float* X; unsigned short* Y;
    if (z == 0)      { X = q; Y = qh; }
    else if (z == 1) { X = k; Y = kpad; }
    else             { X = v; Y = vpad; }
    const unsigned short* Wb = wb + z * 65536;
    X += (size_t)b * CH * HWSZ;
    const size_t pixstride = (z == 0) ? (size_t)HWSZ : (size_t)PPIX;
    Y += (size_t)b * NHEAD * pixstride * DHEAD;

    const int lane = t & 63;
    const int wid  = t >> 6;   // m-quadrant / staging channel group
    const int lrow = lane & 15;
    const int lkg  = lane >> 4;
    const int pB   = t & 63;   // staging pixel (lane)
    const int cg   = t >> 6;   // staging 64-channel group

    // ---- stage ALL of B: 64 channels per thread, 8 chunks of 8 ----
#pragma unroll
    for (int i = 0; i < 8; ++i) {
        const float* xp = X + (size_t)((cg * 8 + i) * 8) * HWSZ + p0 + pB;
        float fv[8];
#pragma unroll
        for (int j = 0; j < 8; ++j) fv[j] = xp[(size_t)j * HWSZ];
        uint4 u;
        u.x = pkbf(fv[0], fv[1]); u.y = pkbf(fv[2], fv[3]);
        u.z = pkbf(fv[4], fv[5]); u.w = pkbf(fv[6], fv[7]);
        *reinterpret_cast<uint4*>(&lB[pB * ROWS + (cg * 8 + i) * 8]) = u;
    }

    // A prologue prefetch (ks=0) overlaps the LDS-write drain
    bf16x8 afc[4], afn[4];
#pragma unroll
    for (int m = 0; m < 4; ++m)
        afc[m] = *reinterpret_cast<const bf16x8*>(Wb + (wid * 64 + m * 16 + lrow) * 256 + lkg * 8);

    f32x4 acc[4][4];
    const f32x4 zero = {0.f, 0.f, 0.f, 0.f};
#pragma unroll
    for (int m = 0; m < 4; ++m)
#pragma unroll
        for (int n = 0; n < 4; ++n) acc[m][n] = zero;

    __syncthreads();   // the ONLY barrier

#pragma unroll
    for (int ks = 0; ks < 8; ++ks) {
        if (ks < 7) {
#pragma unroll
            for (int m = 0; m < 4; ++m)
                afn[m] = *reinterpret_cast<const bf16x8*>(Wb + (wid * 64 + m * 16 + lrow) * 256 + (ks + 1) * 32 + lkg * 8);
        }
        bf16x8 bfv[4];
#pragma unroll
        for (int n = 0; n < 4; ++n)
            bfv[n] = *reinterpret_cast<const bf16x8*>(&lB[(n * 16 + lrow) * ROWS + (ks * 4 + lkg) * 8]);
#pragma unroll
        for (int m = 0; m < 4; ++m)
#pragma unroll
            for (int n = 0; n < 4; ++n)
                acc[m][n] = __builtin_amdgcn_mfma_f32_16x16x32_bf16(afc[m], bfv[n], acc[m][n], 0, 0, 0);
#pragma unroll
        for (int m = 0; m < 4; ++m) afc[m] = afn[m];
    }

    const int lr = lane >> 4, lc = lane & 15;
#pragma unroll
    for (int m = 0; m < 4; ++m)
#pragma unroll
        for (int n = 0; n < 4; ++n) {
            int o = wid * 64 + m * 16 + lr * 4;
            int hh_ = o >> 5, d0 = o & 31;
            int p = p0 + n * 16 + lc;
            ushort4 pk;
            pk.x = f2h(acc[m][n][0]); pk.y = f2h(acc[m][n][1]);
            pk.z = f2h(acc[m][n][2]); pk.w = f2h(acc[m][n][3]);
            size_t pix;
            if (z == 0) pix = (size_t)hh_ * HWSZ + p;
            else { int row = p >> 7, col = p & 127; pix = (size_t)hh_ * PPIX + (size_t)(row + 2) * PW + (col + 2); }
            *reinterpret_cast<ushort4*>(&Y[pix * DHEAD + d0]) = pk;
        }
}

// ---------------------------------------------------------------------------
// Kernel 2: local 5x5 attention — 4 lanes per pixel, contiguous 1KB/wave.
// Output converted to BF16 (pixel-major, in place over qh).
// ---------------------------------------------------------------------------
__global__ __launch_bounds__(1024)
void attn_kernel(unsigned short* __restrict__ qh,
                 const unsigned short* __restrict__ kpad,
                 const unsigned short* __restrict__ vpad)
{
    const int t = threadIdx.x;
    const int swz = (blockIdx.x & 7) * 1024 + (blockIdx.x >> 3);
    const int bh = swz >> 6;
    const int tile = swz & 63;
    const int x0 = (tile & 7) * 16, y0 = (tile >> 3) * 16;
    const int qc = t & 3;
    const int px = (t >> 2) & 15;
    const int py = t >> 6;
    const int gx = x0 + px, gy = y0 + py;

    unsigned short* qp = qh + ((size_t)bh * HWSZ + gy * WW + gx) * DHEAD + qc * 8;
    const unsigned short* kb = kpad + (size_t)bh * PPIX * DHEAD + qc * 8;
    const unsigned short* vb = vpad + (size_t)bh * PPIX * DHEAD + qc * 8;

    union { uint4 u; h2v h2[4]; } Q;
    Q.u = *reinterpret_cast<const uint4*>(qp);

    float ew[25];
#pragma unroll
    for (int wy = 0; wy < 5; ++wy) {
        const unsigned short* krow = kb + (size_t)((gy + wy) * PW + gx) * DHEAD;
#pragma unroll
        for (int wx = 0; wx < 5; ++wx) {
            union { uint4 u; h2v h2[4]; } K;
            K.u = *reinterpret_cast<const uint4*>(krow + wx * DHEAD);
            float s = 0.f;
#pragma unroll
            for (int j = 0; j < 4; ++j)
                s = DOT2(Q.h2[j], K.h2[j], s);
            s += __shfl_xor(s, 1);
            s += __shfl_xor(s, 2);
            ew[wy * 5 + wx] = __expf(fmaxf(s, 0.f) * 0.17677669529663687f);
        }
    }

    float sum = 0.f;
#pragma unroll
    for (int i = 0; i < 25; ++i) sum += ew[i];
    const float inv = 1.f / sum;

    union { uint4 u; h2v h2[4]; } A;
    const h2v hz = {(_Float16)0.f, (_Float16)0.f};
#pragma unroll
    for (int j = 0; j < 4; ++j) A.h2[j] = hz;

#pragma unroll
    for (int wy = 0; wy < 5; ++wy) {
        const unsigned short* vrow = vb + (size_t)((gy + wy) * PW + gx) * DHEAD;
#pragma unroll
        for (int wx = 0; wx < 5; ++wx) {
            _Float16 wh = (_Float16)(ew[wy * 5 + wx] * inv);
            h2v w2 = {wh, wh};
            union { uint4 u; h2v h2[4]; } V;
            V.u = *reinterpret_cast<const uint4*>(vrow + wx * DHEAD);
#pragma unroll
            for (int j = 0; j < 4; ++j)
                A.h2[j] += w2 * V.h2[j];
        }
    }

    // f16 acc -> bf16 out (fcln consumes bf16 directly)
    uint4 o;
    o.x = pkbf((float)A.h2[0][0], (float)A.h2[0][1]);
    o.y = pkbf((float)A.h2[1][0], (float)A.h2[1][1]);
    o.z = pkbf((float)A.h2[2][0], (float)A.h2[2][1]);
    o.w = pkbf((float)A.h2[3][0], (float)A.h2[3][1]);
    *reinterpret_cast<uint4*>(qp) = o;
}

// ---------------------------------------------------------------------------
// Kernel 3: o = wfc @ attn_out + residual, LayerNorm. Same single-barrier
// structure: stage full bf16 B-panel (pure uint4 copies, 4 lanes/pixel so
// pixel-major reads coalesce to 16 lines/instr), then barrier-free compute.
// ---------------------------------------------------------------------------
__global__ __launch_bounds__(256)
void fcln_kernel(const unsigned short* __restrict__ ob, const unsigned short* __restrict__ wfcb,
                 const float* __restrict__ qres, const float* __restrict__ lnw,
                 const float* __restrict__ lnb, float* __restrict__ out)
{
    __shared__ __align__(16) unsigned short lB[64 * ROWS];  // 33 KB
    __shared__ float lsum[4][64];
    __shared__ float lssq[4][64];

    const int t = threadIdx.x;
    const int b = blockIdx.y;
    const int p0 = blockIdx.x * 64;

    const int lane = t & 63;
    const int wid  = t >> 6;
    const int lrow = lane & 15;
    const int lkg  = lane >> 4;
    const int pxf  = t >> 2;    // staging pixel (0..63)
    const int qcf  = t & 3;     // staging quarter

    // ---- stage ALL of B: one head-chunk (16B) per iter, contiguous 1KB/wave
#pragma unroll
    for (int h = 0; h < 8; ++h) {
        uint4 bv = *reinterpret_cast<const uint4*>(
            ob + ((size_t)(b * NHEAD + h) * HWSZ + p0 + pxf) * DHEAD + qcf * 8);
        *reinterpret_cast<uint4*>(&lB[pxf * ROWS + (h * 4 + qcf) * 8]) = bv;
    }

    bf16x8 afc[4], afn[4];
#pragma unroll
    for (int m = 0; m < 4; ++m)
        afc[m] = *reinterpret_cast<const bf16x8*>(wfcb + (wid * 64 + m * 16 + lrow) * 256 + lkg * 8);

    f32x4 acc[4][4];
    const f32x4 zero = {0.f, 0.f, 0.f, 0.f};
#pragma unroll
    for (int m = 0; m < 4; ++m)
#pragma unroll
        for (int n = 0; n < 4; ++n) acc[m][n] = zero;

    __syncthreads();   // the ONLY pre-LN barrier

#pragma unroll
    for (int ks = 0; ks < 8; ++ks) {
        if (ks < 7) {
#pragma unroll
            for (int m = 0; m < 4; ++m)
                afn[m] = *reinterpret_cast<const bf16x8*>(wfcb + (wid * 64 + m * 16 + lrow) * 256 + (ks + 1) * 32 + lkg * 8);
        }
        bf16x8 bfv[4];
#pragma unroll
        for (int n = 0; n < 4; ++n)
            bfv[n] = *reinterpret_cast<const bf16x8*>(&lB[(n * 16 + lrow) * ROWS + (ks * 4 + lkg) * 8]);
#pragma unroll
        for (int m = 0; m < 4; ++m)
#pragma unroll
            for (int n = 0; n < 4; ++n)
                acc[m][n] = __builtin_amdgcn_mfma_f32_16x16x32_bf16(afc[m], bfv[n], acc[m][n], 0, 0, 0);
#pragma unroll
        for (int m = 0; m < 4; ++m) afc[m] = afn[m];
    }

    const int lr = lane >> 4, lc = lane & 15;
    const float* qb = qres + (size_t)b * CH * HWSZ;
#pragma unroll
    for (int m = 0; m < 4; ++m)
#pragma unroll
        for (int n = 0; n < 4; ++n)
#pragma unroll
            for (int j = 0; j < 4; ++j) {
                int o = wid * 64 + m * 16 + lr * 4 + j;
                int p = p0 + n * 16 + lc;
                acc[m][n][j] += qb[(size_t)o * HWSZ + p];
            }

    float s[4], s2[4];
#pragma unroll
    for (int n = 0; n < 4; ++n) {
        float a = 0.f, c2 = 0.f;
#pragma unroll
        for (int m = 0; m < 4; ++m)
#pragma unroll
            for (int j = 0; j < 4; ++j) {
                float x = acc[m][n][j];
                a += x; c2 += x * x;
            }
        a  += __shfl_xor(a, 16);  a  += __shfl_xor(a, 32);
        c2 += __shfl_xor(c2, 16); c2 += __shfl_xor(c2, 32);
        s[n] = a; s2[n] = c2;
    }
    if (lane < 16) {
#pragma unroll
        for (int n = 0; n < 4; ++n) {
            lsum[wid][n * 16 + lane] = s[n];
            lssq[wid][n * 16 + lane] = s2[n];
        }
    }
    __syncthreads();

    float mu[4], rs[4];
#pragma unroll
    for (int n = 0; n < 4; ++n) {
        int p = n * 16 + lc;
        float ts = lsum[0][p] + lsum[1][p] + lsum[2][p] + lsum[3][p];
        float tq = lssq[0][p] + lssq[1][p] + lssq[2][p] + lssq[3][p];
        float m_ = ts * (1.f / 256.f);
        float v_ = tq * (1.f / 256.f) - m_ * m_;
        mu[n] = m_;
        rs[n] = rsqrtf(v_ + 1e-6f);
    }

    float* op = out + (size_t)b * CH * HWSZ;
#pragma unroll
    for (int m = 0; m < 4; ++m)
#pragma unroll
        for (int j = 0; j < 4; ++j) {
            int o = wid * 64 + m * 16 + lr * 4 + j;
            float g = lnw[o], bb = lnb[o];
#pragma unroll
            for (int n = 0; n < 4; ++n) {
                int p = p0 + n * 16 + lc;
                op[(size_t)o * HWSZ + p] = (acc[m][n][j] - mu[n]) * rs[n] * g + bb;
            }
        }
}

extern "C" void kernel_launch(void* const* d_in, const int* in_sizes, int n_in,
                              void* d_out, int out_size, void* d_ws, size_t ws_size,
                              hipStream_t stream) {
    const float* q   = (const float*)d_in[0];
    const float* k   = (const float*)d_in[1];
    const float* v   = (const float*)d_in[2];
    const float* wq  = (const float*)d_in[3];
    const float* wk  = (const float*)d_in[4];
    const float* wv  = (const float*)d_in[5];
    const float* wfc = (const float*)d_in[6];
    const float* lnw = (const float*)d_in[7];
    const float* lnb = (const float*)d_in[8];

    const size_t qsz = (size_t)BATCH * NHEAD * HWSZ * DHEAD;   // 67,108,864
    const size_t psz = (size_t)BATCH * NHEAD * PPIX * DHEAD;   // 71,368,704
    if (ws_size < (qsz + 2 * psz + 4 * 65536) * sizeof(unsigned short)) return;

    unsigned short* qh = (unsigned short*)d_ws;   // q proj (f16), then attn output (bf16, in place)
    unsigned short* kp = qh + qsz;
    unsigned short* vp = kp + psz;
    unsigned short* wb = vp + psz;                // 512KB bf16 weight stash (wq|wk|wv|wfc)

    zpad_kernel<<<256, 256, 0, stream>>>(kp, vp);
    prep_kernel<<<dim3(32, 4), 256, 0, stream>>>(wq, wk, wv, wfc, wb);
    proj_kernel<<<dim3(HWSZ / 64, BATCH, 3), 256, 0, stream>>>(q, k, v, wb, qh, kp, vp);
    attn_kernel<<<8192, 1024, 0, stream>>>(qh, kp, vp);
    fcln_kernel<<<dim3(HWSZ / 64, BATCH), 256, 0, stream>>>(qh, wb + 3 * 65536, q, lnw, lnb, (float*)d_out);
}